// Round 3
// baseline (481.646 us; speedup 1.0000x reference)
//
#include <hip/hip_runtime.h>
#include <hip/hip_cooperative_groups.h>
#include <math.h>

namespace cg = cooperative_groups;

#define CDIM 1024
#define TC   3072
#define NIN  2048   // input rows per batch (class token handled separately)

// workspace float offsets (every slot written before read; no zero-init needed)
#define OFF_Q0P 0           // [16][1024] q0 i-chunk partials
#define OFF_WS  16384       // [4][1024]  Ws[h][c]
#define OFF_PS  20480       // [1024][4]  per-chunk exp-sums
#define OFF_PY  24576       // [1024][4096] per-chunk weighted x-sums (16 MB)
#define OFF_YB  4218880     // [8][4][1024] normalized attention-averaged rows
#define OFF_OC  4251648     // [8][1024]  oc rows

// ---------- phase bodies (virtual-block indexed; work for ANY grid size) ----------

__device__ __forceinline__ void phase1(int vb, int tid, float* lds,
        const float* __restrict__ t, const float* __restrict__ W,
        float* __restrict__ wsb) {
    // q0p[ic][j] = sum_{i in 64-chunk ic} t[i] * Wq[i][j]   (vb < 256)
    int lane = tid & 63, wave = tid >> 6;
    int ic = vb >> 4, jc = vb & 15;          // 16 i-chunks x 16 j-chunks
    int j = jc * 64 + lane;
    int i0 = ic * 64 + wave * 16;            // waves split i
    float acc = 0.f;
#pragma unroll
    for (int ii = 0; ii < 16; ++ii)
        acc += t[i0 + ii] * W[(size_t)(i0 + ii) * TC + j];
    lds[wave * 64 + lane] = acc;
    __syncthreads();
    if (wave == 0)
        wsb[OFF_Q0P + ic * CDIM + j] =
            lds[lane] + lds[64 + lane] + lds[128 + lane] + lds[192 + lane];
}

__device__ __forceinline__ void phase2(int vb, int tid, float* lds,
        const float* __restrict__ W, const float* __restrict__ bqkv,
        float* __restrict__ wsb) {
    // Ws[h][c=vb] = sum_d Wk[c][h*256+d] * (q0[d]+bq[d])   (vb < 1024)
    int lane = tid & 63, wave = tid >> 6;
    for (int d = tid; d < CDIM; d += 256) {  // stage q = q0+bq in LDS
        float s = bqkv[d];
#pragma unroll
        for (int ic = 0; ic < 16; ++ic) s += wsb[OFF_Q0P + ic * CDIM + d];
        lds[d] = s;
    }
    __syncthreads();
    int c = vb, h = wave;                    // 4 waves = 4 heads
    float4 wv = *(const float4*)&W[(size_t)c * TC + CDIM + h * 256 + lane * 4];
    float4 qv = *(const float4*)&lds[h * 256 + lane * 4];
    float a = wv.x * qv.x + wv.y * qv.y + wv.z * qv.z + wv.w * qv.w;
    for (int off = 32; off; off >>= 1) a += __shfl_down(a, off);
    if (lane == 0) wsb[OFF_WS + h * CDIM + c] = a;
}

__device__ __forceinline__ void phase3(int vb, int tid, float* lds,
        const float* __restrict__ x, float* __restrict__ wsb) {
    // single pass over x: exp(score) + weighted row-sum. vb = (b, 16-row chunk).
    // No max-shift (scores O(+-5), verified absmax ~1e-6 in prior rounds).
    int lane = tid & 63, wave = tid >> 6;
    int b = vb >> 7, blkc = vb & 127;
    float4 wsr[4][4];
#pragma unroll
    for (int k = 0; k < 4; ++k)
#pragma unroll
        for (int h = 0; h < 4; ++h)
            wsr[k][h] = *(const float4*)&wsb[OFF_WS + h * CDIM + k * 256 + lane * 4];

    float s[4] = {0.f, 0.f, 0.f, 0.f};
    float4 y[4][4];
#pragma unroll
    for (int h = 0; h < 4; ++h)
#pragma unroll
        for (int k = 0; k < 4; ++k) y[h][k] = make_float4(0.f, 0.f, 0.f, 0.f);

    const float* base = x + ((size_t)b * NIN + blkc * 16 + wave * 4) * CDIM;
#pragma unroll
    for (int i = 0; i < 4; ++i) {
        const float* row = base + (size_t)i * CDIM;
        float4 xv[4];
#pragma unroll
        for (int k = 0; k < 4; ++k) xv[k] = *(const float4*)&row[k * 256 + lane * 4];
        float e[4];
#pragma unroll
        for (int h = 0; h < 4; ++h) {
            float a = 0.f;
#pragma unroll
            for (int k = 0; k < 4; ++k)
                a += xv[k].x * wsr[k][h].x + xv[k].y * wsr[k][h].y +
                     xv[k].z * wsr[k][h].z + xv[k].w * wsr[k][h].w;
            for (int off = 1; off < 64; off <<= 1) a += __shfl_xor(a, off);
            e[h] = __expf(a * 0.0625f);   // Dh=256 -> 1/16; +ck cancels in softmax
        }
#pragma unroll
        for (int h = 0; h < 4; ++h) {
            float f = e[h];
            s[h] += f;
#pragma unroll
            for (int k = 0; k < 4; ++k) {
                y[h][k].x += f * xv[k].x; y[h][k].y += f * xv[k].y;
                y[h][k].z += f * xv[k].z; y[h][k].w += f * xv[k].w;
            }
        }
    }

    // scalar sums merge via lds[0..15], PS write, then ybuf merge in lds[0..4095]
    if (lane == 0)
#pragma unroll
        for (int h = 0; h < 4; ++h) lds[wave * 4 + h] = s[h];
    __syncthreads();
    if (tid < 4)
        wsb[OFF_PS + vb * 4 + tid] = lds[tid] + lds[4 + tid] + lds[8 + tid] + lds[12 + tid];
    __syncthreads();
    for (int idx = tid; idx < 4096; idx += 256) lds[idx] = 0.f;
    __syncthreads();
    for (int w = 0; w < 4; ++w) {
        if (wave == w) {
#pragma unroll
            for (int h = 0; h < 4; ++h)
#pragma unroll
                for (int k = 0; k < 4; ++k) {
                    float4* dst = (float4*)&lds[h * CDIM + k * 256 + lane * 4];
                    float4 v = *dst;
                    v.x += y[h][k].x; v.y += y[h][k].y;
                    v.z += y[h][k].z; v.w += y[h][k].w;
                    *dst = v;
                }
        }
        __syncthreads();
    }
    for (int idx = tid; idx < 4096; idx += 256)
        wsb[OFF_PY + (size_t)vb * 4096 + idx] = lds[idx];
}

__device__ __forceinline__ void phase4(int vb, int tid, float* lds,
        const float* __restrict__ t, float* __restrict__ wsb) {
    // combine 128 chunk-partials + class-token term -> normalized ybar (vb < 1024)
    int lane = tid & 63, wave = tid >> 6;
    int b = vb >> 7, h = (vb >> 5) & 3, cq = vb & 31;
    // sc0 = (t . Ws_h)/16 (redundant per block, cheap)
    float4 tv = *(const float4*)&t[tid * 4];
    float4 wv = *(const float4*)&wsb[OFF_WS + h * CDIM + tid * 4];
    float p = tv.x * wv.x + tv.y * wv.y + tv.z * wv.z + tv.w * wv.w;
    for (int off = 1; off < 64; off <<= 1) p += __shfl_xor(p, off);
    float sv = 0.f;
    if (wave == 0) {   // sum 128 chunk exp-sums: 2 per lane
        sv = wsb[OFF_PS + (size_t)(b * 128 + lane) * 4 + h] +
             wsb[OFF_PS + (size_t)(b * 128 + 64 + lane) * 4 + h];
        for (int off = 1; off < 64; off <<= 1) sv += __shfl_xor(sv, off);
    }
    if (lane == 0) lds[256 + wave] = p;
    if (tid == 0) lds[260] = sv;
    __syncthreads();
    float sc0 = (lds[256] + lds[257] + lds[258] + lds[259]) * 0.0625f;
    float e0 = __expf(sc0);
    float S = lds[260] + e0;

    int col = cq * 32 + (tid & 31), ps = tid >> 5;   // 8 partial-slices of 16
    float acc = 0.f;
#pragma unroll 4
    for (int jj = 0; jj < 16; ++jj)
        acc += wsb[OFF_PY + (size_t)(b * 128 + ps * 16 + jj) * 4096 + h * CDIM + col];
    lds[ps * 32 + (tid & 31)] = acc;
    __syncthreads();
    if (ps == 0) {
        float tot = e0 * t[col];
#pragma unroll
        for (int s8 = 0; s8 < 8; ++s8) tot += lds[s8 * 32 + (tid & 31)];
        wsb[OFF_YB + ((size_t)b * 4 + h) * CDIM + col] = tot / S;
    }
}

__device__ __forceinline__ void phase5(int vb, int tid, float* lds,
        const float* __restrict__ W, const float* __restrict__ bqkv,
        float* __restrict__ wsb) {
    // oc[b][c'] = ybar[b][h(c')] . Wqkv[:, 2C+c'] + bq   (vb < 256)
    int b = vb & 7, jc = vb >> 3;            // 8 b x 32 c'-chunks of 32
    int hh = jc >> 3;                        // head of this c'-chunk
    for (int d = tid; d < CDIM; d += 256)
        lds[d] = wsb[OFF_YB + ((size_t)b * 4 + hh) * CDIM + d];
    __syncthreads();
    int cp = jc * 32 + (tid & 31), cs = tid >> 5;   // 8 c-segments of 128
    const float* wcol = &W[2 * CDIM + cp];
    float acc = 0.f;
#pragma unroll 4
    for (int cc = 0; cc < 128; ++cc) {
        int c = cs * 128 + cc;
        acc += lds[c] * wcol[(size_t)c * TC];
    }
    lds[1024 + cs * 32 + (tid & 31)] = acc;  // disjoint from staged row
    __syncthreads();
    if (cs == 0) {
        float a = 0.f;
#pragma unroll
        for (int s8 = 0; s8 < 8; ++s8) a += lds[1024 + s8 * 32 + (tid & 31)];
        wsb[OFF_OC + (size_t)b * CDIM + cp] = a + bqkv[2 * CDIM + cp];
    }
}

__device__ __forceinline__ void phase6(int vb, int tid, float* lds,
        const float* __restrict__ Wv, const float* __restrict__ bv,
        const float* __restrict__ wsb, float* __restrict__ out) {
    // out[b][j] = oc[b] . Wv[:, j] + bv[j]   (vb < 256; each element written once)
    int b = vb & 7, jc = vb >> 3;
    for (int d = tid; d < CDIM; d += 256)
        lds[d] = wsb[OFF_OC + (size_t)b * CDIM + d];
    __syncthreads();
    int j = jc * 32 + (tid & 31), cs = tid >> 5;
    float acc = 0.f;
#pragma unroll 4
    for (int cc = 0; cc < 128; ++cc) {
        int c = cs * 128 + cc;
        acc += lds[c] * Wv[(size_t)c * CDIM + j];
    }
    lds[1024 + cs * 32 + (tid & 31)] = acc;
    __syncthreads();
    if (cs == 0) {
        float a = 0.f;
#pragma unroll
        for (int s8 = 0; s8 < 8; ++s8) a += lds[1024 + s8 * 32 + (tid & 31)];
        out[(size_t)b * CDIM + j] = a + bv[j];
    }
}

// ---------- cooperative fused kernel (grid-stride: correct for ANY grid) ----------
__global__ __launch_bounds__(256, 4) void k_fused(
    const float* __restrict__ x, const float* __restrict__ t,
    const float* __restrict__ W, const float* __restrict__ bqkv,
    const float* __restrict__ Wv, const float* __restrict__ bv,
    float* __restrict__ wsb, float* __restrict__ out)
{
    cg::grid_group grid = cg::this_grid();
    __shared__ float lds[4096];   // exactly 16 KB
    const int tid = threadIdx.x, nb = gridDim.x;

    for (int vb = blockIdx.x; vb < 256; vb += nb) { phase1(vb, tid, lds, t, W, wsb); __syncthreads(); }
    grid.sync();
    for (int vb = blockIdx.x; vb < 1024; vb += nb) { phase2(vb, tid, lds, W, bqkv, wsb); __syncthreads(); }
    grid.sync();
    for (int vb = blockIdx.x; vb < 1024; vb += nb) { phase3(vb, tid, lds, x, wsb); __syncthreads(); }
    grid.sync();
    for (int vb = blockIdx.x; vb < 1024; vb += nb) { phase4(vb, tid, lds, t, wsb); __syncthreads(); }
    grid.sync();
    for (int vb = blockIdx.x; vb < 256; vb += nb) { phase5(vb, tid, lds, W, bqkv, wsb); __syncthreads(); }
    grid.sync();
    for (int vb = blockIdx.x; vb < 256; vb += nb) { phase6(vb, tid, lds, Wv, bv, wsb, out); __syncthreads(); }
}

// ---------- fallback: 6 plain dispatches sharing the same phase bodies ----------
template <int P>
__global__ __launch_bounds__(256) void k_phase(
    const float* __restrict__ x, const float* __restrict__ t,
    const float* __restrict__ W, const float* __restrict__ bqkv,
    const float* __restrict__ Wv, const float* __restrict__ bv,
    float* __restrict__ wsb, float* __restrict__ out)
{
    __shared__ float lds[4096];
    const int tid = threadIdx.x, vb = blockIdx.x;
    if constexpr (P == 1) phase1(vb, tid, lds, t, W, wsb);
    else if constexpr (P == 2) phase2(vb, tid, lds, W, bqkv, wsb);
    else if constexpr (P == 3) phase3(vb, tid, lds, x, wsb);
    else if constexpr (P == 4) phase4(vb, tid, lds, t, wsb);
    else if constexpr (P == 5) phase5(vb, tid, lds, W, bqkv, wsb);
    else phase6(vb, tid, lds, Wv, bv, wsb, out);
}

extern "C" void kernel_launch(void* const* d_in, const int* in_sizes, int n_in,
                              void* d_out, int out_size, void* d_ws, size_t ws_size,
                              hipStream_t stream) {
    const float* x    = (const float*)d_in[0];   // [8,2048,1024]
    const float* t    = (const float*)d_in[1];   // [1,1,1024]
    const float* W    = (const float*)d_in[2];   // [1024,3072]
    const float* bqkv = (const float*)d_in[3];   // [3072]
    const float* Wv   = (const float*)d_in[4];   // [1024,1024]
    const float* bv   = (const float*)d_in[5];   // [1024]
    float* wsb = (float*)d_ws;
    float* out = (float*)d_out;                  // [8,1024] fp32

    void* args[] = {(void*)&x, (void*)&t, (void*)&W, (void*)&bqkv,
                    (void*)&Wv, (void*)&bv, (void*)&wsb, (void*)&out};

    // Negotiate the cooperative grid ONCE: query what actually co-resides,
    // launch exactly that (grid-stride keeps any size correct). -1 = fallback.
    static int coopGrid = 0;
    if (coopGrid == 0) {
        int mb = 0;
        hipError_t qe = hipOccupancyMaxActiveBlocksPerMultiprocessor(&mb, k_fused, 256, 0);
        if (qe != hipSuccess || mb < 1) coopGrid = -1;
        else coopGrid = (mb >= 4) ? 1024 : mb * 256;   // 256 CUs on MI355X
    }
    if (coopGrid > 0) {
        hipError_t e = hipLaunchCooperativeKernel(reinterpret_cast<void*>(k_fused),
                                                  dim3(coopGrid), dim3(256), args, 0, stream);
        if (e == hipSuccess) return;
        coopGrid = -1;   // never retry; fall through to plain dispatches
    }
    k_phase<1><<<256,  256, 0, stream>>>(x, t, W, bqkv, Wv, bv, wsb, out);
    k_phase<2><<<1024, 256, 0, stream>>>(x, t, W, bqkv, Wv, bv, wsb, out);
    k_phase<3><<<1024, 256, 0, stream>>>(x, t, W, bqkv, Wv, bv, wsb, out);
    k_phase<4><<<1024, 256, 0, stream>>>(x, t, W, bqkv, Wv, bv, wsb, out);
    k_phase<5><<<256,  256, 0, stream>>>(x, t, W, bqkv, Wv, bv, wsb, out);
    k_phase<6><<<256,  256, 0, stream>>>(x, t, W, bqkv, Wv, bv, wsb, out);
}

// Round 4
// 164.964 us; speedup vs baseline: 2.9197x; 2.9197x over previous
//
#include <hip/hip_runtime.h>
#include <hip/hip_cooperative_groups.h>
#include <math.h>

namespace cg = cooperative_groups;

#define CDIM 1024
#define TC   3072
#define NIN  2048   // input rows per batch (class token handled separately)

// workspace float offsets (every slot written before read; no zero-init needed)
#define OFF_Q0P 0           // [16][1024] q0 i-chunk partials
#define OFF_WS  16384       // [4][1024]  Ws[h][c]
#define OFF_PS  20480       // [1024][4]  per-chunk exp-sums
#define OFF_PY  24576       // [1024][4096] per-chunk weighted x-sums (16 MB)
#define OFF_YB  4218880     // [8][4][1024] normalized attention-averaged rows
#define OFF_OC  4251648     // [8][1024]  oc rows

// Cooperative kernel, HARD grid = 1024 x 256 (4 blocks/CU, 4 waves/SIMD).
// Straight-line bodies, __launch_bounds__(256) ONLY: the round-1-proven
// spill-free codegen shape (VGPR=108). (256,4) caused VGPR=64 + 80MB of
// scratch spills in round 3 -- do not reintroduce.
__global__ __launch_bounds__(256) void k_fused(
    const float* __restrict__ x, const float* __restrict__ t,
    const float* __restrict__ W, const float* __restrict__ bqkv,
    const float* __restrict__ Wv, const float* __restrict__ bv,
    float* __restrict__ wsb, float* __restrict__ out)
{
    cg::grid_group grid = cg::this_grid();
    const int bid = blockIdx.x, tid = threadIdx.x;
    const int lane = tid & 63, wave = tid >> 6;
    __shared__ float lds[4096];   // exactly 16 KB

    // ---- P1 (bid<256): q0p[ic][j] = sum_{i in 64-chunk ic} t[i]*Wq[i][j] ----
    if (bid < 256) {
        int ic = bid >> 4, jc = bid & 15;        // 16 i-chunks x 16 j-chunks
        int j = jc * 64 + lane;
        int i0 = ic * 64 + wave * 16;            // waves split i
        float acc = 0.f;
#pragma unroll
        for (int ii = 0; ii < 16; ++ii)
            acc += t[i0 + ii] * W[(size_t)(i0 + ii) * TC + j];
        lds[wave * 64 + lane] = acc;
        __syncthreads();
        if (wave == 0)
            wsb[OFF_Q0P + ic * CDIM + j] =
                lds[lane] + lds[64 + lane] + lds[128 + lane] + lds[192 + lane];
    }
    grid.sync();

    // ---- P2 (all 1024): Ws[h][c=bid] = sum_d Wk[c][h*256+d] * (q0[d]+bq[d]) ----
    {
        for (int d = tid; d < CDIM; d += 256) {  // stage q = q0+bq in LDS
            float s = bqkv[d];
#pragma unroll
            for (int ic = 0; ic < 16; ++ic) s += wsb[OFF_Q0P + ic * CDIM + d];
            lds[d] = s;
        }
        __syncthreads();
        int c = bid, h = wave;                   // FIXED: one c per block, 4 waves = 4 heads
        float4 wv = *(const float4*)&W[(size_t)c * TC + CDIM + h * 256 + lane * 4];
        float4 qv = *(const float4*)&lds[h * 256 + lane * 4];
        float a = wv.x * qv.x + wv.y * qv.y + wv.z * qv.z + wv.w * qv.w;
        for (int off = 32; off; off >>= 1) a += __shfl_down(a, off);
        if (lane == 0) wsb[OFF_WS + h * CDIM + c] = a;
        __syncthreads();
    }
    grid.sync();

    // ---- P3 (all 1024): single pass over x: exp(score) + weighted row-sum ----
    // block = (b, 16-row chunk); wave owns 4 rows. No max-shift (scores O(+-5)).
    {
        int b = bid >> 7, blkc = bid & 127;
        float4 wsr[4][4];
#pragma unroll
        for (int k = 0; k < 4; ++k)
#pragma unroll
            for (int h = 0; h < 4; ++h)
                wsr[k][h] = *(const float4*)&wsb[OFF_WS + h * CDIM + k * 256 + lane * 4];

        float s[4] = {0.f, 0.f, 0.f, 0.f};
        float4 y[4][4];
#pragma unroll
        for (int h = 0; h < 4; ++h)
#pragma unroll
            for (int k = 0; k < 4; ++k) y[h][k] = make_float4(0.f, 0.f, 0.f, 0.f);

        const float* base = x + ((size_t)b * NIN + blkc * 16 + wave * 4) * CDIM;
#pragma unroll
        for (int i = 0; i < 4; ++i) {
            const float* row = base + (size_t)i * CDIM;
            float4 xv[4];
#pragma unroll
            for (int k = 0; k < 4; ++k) xv[k] = *(const float4*)&row[k * 256 + lane * 4];
            float e[4];
#pragma unroll
            for (int h = 0; h < 4; ++h) {
                float a = 0.f;
#pragma unroll
                for (int k = 0; k < 4; ++k)
                    a += xv[k].x * wsr[k][h].x + xv[k].y * wsr[k][h].y +
                         xv[k].z * wsr[k][h].z + xv[k].w * wsr[k][h].w;
                for (int off = 1; off < 64; off <<= 1) a += __shfl_xor(a, off);
                e[h] = __expf(a * 0.0625f);   // Dh=256 -> 1/16; +ck cancels in softmax
            }
#pragma unroll
            for (int h = 0; h < 4; ++h) {
                float f = e[h];
                s[h] += f;
#pragma unroll
                for (int k = 0; k < 4; ++k) {
                    y[h][k].x += f * xv[k].x; y[h][k].y += f * xv[k].y;
                    y[h][k].z += f * xv[k].z; y[h][k].w += f * xv[k].w;
                }
            }
        }

        // scalar exp-sums merge via lds[0..15] (PS written BEFORE ybuf zeroing)
        if (lane == 0)
#pragma unroll
            for (int h = 0; h < 4; ++h) lds[wave * 4 + h] = s[h];
        __syncthreads();
        if (tid < 4)
            wsb[OFF_PS + bid * 4 + tid] =
                lds[tid] + lds[4 + tid] + lds[8 + tid] + lds[12 + tid];
        __syncthreads();
        for (int idx = tid; idx < 4096; idx += 256) lds[idx] = 0.f;
        __syncthreads();
        for (int w = 0; w < 4; ++w) {
            if (wave == w) {
#pragma unroll
                for (int h = 0; h < 4; ++h)
#pragma unroll
                    for (int k = 0; k < 4; ++k) {
                        float4* dst = (float4*)&lds[h * CDIM + k * 256 + lane * 4];
                        float4 v = *dst;
                        v.x += y[h][k].x; v.y += y[h][k].y;
                        v.z += y[h][k].z; v.w += y[h][k].w;
                        *dst = v;
                    }
            }
            __syncthreads();
        }
        for (int idx = tid; idx < 4096; idx += 256)
            wsb[OFF_PY + (size_t)bid * 4096 + idx] = lds[idx];
    }
    grid.sync();

    // ---- P4 (all 1024): combine 128 chunk-partials + class-token -> ybar ----
    {
        int b = bid >> 7, h = (bid >> 5) & 3, cq = bid & 31;
        // sc0 = (t . Ws_h)/16 (redundant per block, cheap)
        float4 tv = *(const float4*)&t[tid * 4];
        float4 wv = *(const float4*)&wsb[OFF_WS + h * CDIM + tid * 4];
        float p = tv.x * wv.x + tv.y * wv.y + tv.z * wv.z + tv.w * wv.w;
        for (int off = 1; off < 64; off <<= 1) p += __shfl_xor(p, off);
        float sv = 0.f;
        if (wave == 0) {   // sum 128 chunk exp-sums: 2 per lane
            sv = wsb[OFF_PS + (size_t)(b * 128 + lane) * 4 + h] +
                 wsb[OFF_PS + (size_t)(b * 128 + 64 + lane) * 4 + h];
            for (int off = 1; off < 64; off <<= 1) sv += __shfl_xor(sv, off);
        }
        if (lane == 0) lds[512 + wave] = p;
        if (tid == 0) lds[516] = sv;
        __syncthreads();
        float sc0 = (lds[512] + lds[513] + lds[514] + lds[515]) * 0.0625f;
        float e0 = __expf(sc0);
        float S = lds[516] + e0;

        int col = cq * 32 + (tid & 31), ps = tid >> 5;   // 8 partial-slices of 16
        float acc = 0.f;
#pragma unroll 4
        for (int jj = 0; jj < 16; ++jj)
            acc += wsb[OFF_PY + (size_t)(b * 128 + ps * 16 + jj) * 4096 + h * CDIM + col];
        __syncthreads();
        lds[ps * 32 + (tid & 31)] = acc;
        __syncthreads();
        if (ps == 0) {
            float tot = e0 * t[col];
#pragma unroll
            for (int s8 = 0; s8 < 8; ++s8) tot += lds[s8 * 32 + (tid & 31)];
            wsb[OFF_YB + ((size_t)b * 4 + h) * CDIM + col] = tot / S;
        }
    }
    grid.sync();

    // ---- P5 (bid<256): oc[b][c'] = ybar[b][h(c')] . Wqkv[:, 2C+c'] + bq ----
    if (bid < 256) {
        int b = bid & 7, jc = bid >> 3;          // 8 b x 32 c'-chunks of 32
        int hh = jc >> 3;                        // head of this c'-chunk
        for (int d = tid; d < CDIM; d += 256)
            lds[d] = wsb[OFF_YB + ((size_t)b * 4 + hh) * CDIM + d];
        __syncthreads();
        int cp = jc * 32 + (tid & 31), cs = tid >> 5;   // 8 c-segments of 128
        const float* wcol = &W[2 * CDIM + cp];
        float acc = 0.f;
#pragma unroll 4
        for (int cc = 0; cc < 128; ++cc) {
            int c = cs * 128 + cc;
            acc += lds[c] * wcol[(size_t)c * TC];
        }
        lds[1024 + cs * 32 + (tid & 31)] = acc;  // disjoint from staged row
        __syncthreads();
        if (cs == 0) {
            float a = 0.f;
#pragma unroll
            for (int s8 = 0; s8 < 8; ++s8) a += lds[1024 + s8 * 32 + (tid & 31)];
            wsb[OFF_OC + (size_t)b * CDIM + cp] = a + bqkv[2 * CDIM + cp];
        }
    }
    grid.sync();

    // ---- P6 (bid<256): out[b][j] = oc[b] . Wv[:, j] + bv[j] ----
    if (bid < 256) {
        int b = bid & 7, jc = bid >> 3;
        for (int d = tid; d < CDIM; d += 256)
            lds[d] = wsb[OFF_OC + (size_t)b * CDIM + d];
        __syncthreads();
        int j = jc * 32 + (tid & 31), cs = tid >> 5;
        float acc = 0.f;
#pragma unroll 4
        for (int cc = 0; cc < 128; ++cc) {
            int c = cs * 128 + cc;
            acc += lds[c] * Wv[(size_t)c * CDIM + j];
        }
        lds[1024 + cs * 32 + (tid & 31)] = acc;
        __syncthreads();
        if (cs == 0) {
            float a = 0.f;
#pragma unroll
            for (int s8 = 0; s8 < 8; ++s8) a += lds[1024 + s8 * 32 + (tid & 31)];
            out[(size_t)b * CDIM + j] = a + bv[j];
        }
    }
}

// ---------- fallback: 6 plain dispatches, bodies identical to the phases ----------
__global__ __launch_bounds__(256) void k_p1(const float* __restrict__ t,
        const float* __restrict__ W, float* __restrict__ wsb) {
    __shared__ float lds[256];
    int tid = threadIdx.x, lane = tid & 63, wave = tid >> 6, bid = blockIdx.x;
    int ic = bid >> 4, jc = bid & 15;
    int j = jc * 64 + lane, i0 = ic * 64 + wave * 16;
    float acc = 0.f;
#pragma unroll
    for (int ii = 0; ii < 16; ++ii)
        acc += t[i0 + ii] * W[(size_t)(i0 + ii) * TC + j];
    lds[wave * 64 + lane] = acc;
    __syncthreads();
    if (wave == 0)
        wsb[OFF_Q0P + ic * CDIM + j] =
            lds[lane] + lds[64 + lane] + lds[128 + lane] + lds[192 + lane];
}

__global__ __launch_bounds__(256) void k_p2(const float* __restrict__ W,
        const float* __restrict__ bqkv, float* __restrict__ wsb) {
    __shared__ float lds[1024];
    int tid = threadIdx.x, lane = tid & 63, wave = tid >> 6, bid = blockIdx.x;
    for (int d = tid; d < CDIM; d += 256) {
        float s = bqkv[d];
#pragma unroll
        for (int ic = 0; ic < 16; ++ic) s += wsb[OFF_Q0P + ic * CDIM + d];
        lds[d] = s;
    }
    __syncthreads();
    int c = bid, h = wave;
    float4 wv = *(const float4*)&W[(size_t)c * TC + CDIM + h * 256 + lane * 4];
    float4 qv = *(const float4*)&lds[h * 256 + lane * 4];
    float a = wv.x * qv.x + wv.y * qv.y + wv.z * qv.z + wv.w * qv.w;
    for (int off = 32; off; off >>= 1) a += __shfl_down(a, off);
    if (lane == 0) wsb[OFF_WS + h * CDIM + c] = a;
}

__global__ __launch_bounds__(256) void k_p3(const float* __restrict__ x,
        float* __restrict__ wsb) {
    __shared__ float lds[4096];
    int tid = threadIdx.x, lane = tid & 63, wave = tid >> 6, bid = blockIdx.x;
    int b = bid >> 7, blkc = bid & 127;
    float4 wsr[4][4];
#pragma unroll
    for (int k = 0; k < 4; ++k)
#pragma unroll
        for (int h = 0; h < 4; ++h)
            wsr[k][h] = *(const float4*)&wsb[OFF_WS + h * CDIM + k * 256 + lane * 4];
    float s[4] = {0.f, 0.f, 0.f, 0.f};
    float4 y[4][4];
#pragma unroll
    for (int h = 0; h < 4; ++h)
#pragma unroll
        for (int k = 0; k < 4; ++k) y[h][k] = make_float4(0.f, 0.f, 0.f, 0.f);
    const float* base = x + ((size_t)b * NIN + blkc * 16 + wave * 4) * CDIM;
#pragma unroll
    for (int i = 0; i < 4; ++i) {
        const float* row = base + (size_t)i * CDIM;
        float4 xv[4];
#pragma unroll
        for (int k = 0; k < 4; ++k) xv[k] = *(const float4*)&row[k * 256 + lane * 4];
        float e[4];
#pragma unroll
        for (int h = 0; h < 4; ++h) {
            float a = 0.f;
#pragma unroll
            for (int k = 0; k < 4; ++k)
                a += xv[k].x * wsr[k][h].x + xv[k].y * wsr[k][h].y +
                     xv[k].z * wsr[k][h].z + xv[k].w * wsr[k][h].w;
            for (int off = 1; off < 64; off <<= 1) a += __shfl_xor(a, off);
            e[h] = __expf(a * 0.0625f);
        }
#pragma unroll
        for (int h = 0; h < 4; ++h) {
            float f = e[h];
            s[h] += f;
#pragma unroll
            for (int k = 0; k < 4; ++k) {
                y[h][k].x += f * xv[k].x; y[h][k].y += f * xv[k].y;
                y[h][k].z += f * xv[k].z; y[h][k].w += f * xv[k].w;
            }
        }
    }
    if (lane == 0)
#pragma unroll
        for (int h = 0; h < 4; ++h) lds[wave * 4 + h] = s[h];
    __syncthreads();
    if (tid < 4)
        wsb[OFF_PS + bid * 4 + tid] = lds[tid] + lds[4 + tid] + lds[8 + tid] + lds[12 + tid];
    __syncthreads();
    for (int idx = tid; idx < 4096; idx += 256) lds[idx] = 0.f;
    __syncthreads();
    for (int w = 0; w < 4; ++w) {
        if (wave == w) {
#pragma unroll
            for (int h = 0; h < 4; ++h)
#pragma unroll
                for (int k = 0; k < 4; ++k) {
                    float4* dst = (float4*)&lds[h * CDIM + k * 256 + lane * 4];
                    float4 v = *dst;
                    v.x += y[h][k].x; v.y += y[h][k].y;
                    v.z += y[h][k].z; v.w += y[h][k].w;
                    *dst = v;
                }
        }
        __syncthreads();
    }
    for (int idx = tid; idx < 4096; idx += 256)
        wsb[OFF_PY + (size_t)bid * 4096 + idx] = lds[idx];
}

__global__ __launch_bounds__(256) void k_p4(const float* __restrict__ t,
        float* __restrict__ wsb) {
    __shared__ float lds[520];
    int tid = threadIdx.x, lane = tid & 63, wave = tid >> 6, bid = blockIdx.x;
    int b = bid >> 7, h = (bid >> 5) & 3, cq = bid & 31;
    float4 tv = *(const float4*)&t[tid * 4];
    float4 wv = *(const float4*)&wsb[OFF_WS + h * CDIM + tid * 4];
    float p = tv.x * wv.x + tv.y * wv.y + tv.z * wv.z + tv.w * wv.w;
    for (int off = 1; off < 64; off <<= 1) p += __shfl_xor(p, off);
    float sv = 0.f;
    if (wave == 0) {
        sv = wsb[OFF_PS + (size_t)(b * 128 + lane) * 4 + h] +
             wsb[OFF_PS + (size_t)(b * 128 + 64 + lane) * 4 + h];
        for (int off = 1; off < 64; off <<= 1) sv += __shfl_xor(sv, off);
    }
    if (lane == 0) lds[512 + wave] = p;
    if (tid == 0) lds[516] = sv;
    __syncthreads();
    float sc0 = (lds[512] + lds[513] + lds[514] + lds[515]) * 0.0625f;
    float e0 = __expf(sc0);
    float S = lds[516] + e0;
    int col = cq * 32 + (tid & 31), ps = tid >> 5;
    float acc = 0.f;
#pragma unroll 4
    for (int jj = 0; jj < 16; ++jj)
        acc += wsb[OFF_PY + (size_t)(b * 128 + ps * 16 + jj) * 4096 + h * CDIM + col];
    lds[ps * 32 + (tid & 31)] = acc;
    __syncthreads();
    if (ps == 0) {
        float tot = e0 * t[col];
#pragma unroll
        for (int s8 = 0; s8 < 8; ++s8) tot += lds[s8 * 32 + (tid & 31)];
        wsb[OFF_YB + ((size_t)b * 4 + h) * CDIM + col] = tot / S;
    }
}

__global__ __launch_bounds__(256) void k_p5(const float* __restrict__ W,
        const float* __restrict__ bqkv, float* __restrict__ wsb) {
    __shared__ float lds[1280];
    int tid = threadIdx.x, bid = blockIdx.x;
    int b = bid & 7, jc = bid >> 3, hh = jc >> 3;
    for (int d = tid; d < CDIM; d += 256)
        lds[d] = wsb[OFF_YB + ((size_t)b * 4 + hh) * CDIM + d];
    __syncthreads();
    int cp = jc * 32 + (tid & 31), cs = tid >> 5;
    const float* wcol = &W[2 * CDIM + cp];
    float acc = 0.f;
#pragma unroll 4
    for (int cc = 0; cc < 128; ++cc) {
        int c = cs * 128 + cc;
        acc += lds[c] * wcol[(size_t)c * TC];
    }
    lds[1024 + cs * 32 + (tid & 31)] = acc;
    __syncthreads();
    if (cs == 0) {
        float a = 0.f;
#pragma unroll
        for (int s8 = 0; s8 < 8; ++s8) a += lds[1024 + s8 * 32 + (tid & 31)];
        wsb[OFF_OC + (size_t)b * CDIM + cp] = a + bqkv[2 * CDIM + cp];
    }
}

__global__ __launch_bounds__(256) void k_p6(const float* __restrict__ Wv,
        const float* __restrict__ bv, const float* __restrict__ wsb,
        float* __restrict__ out) {
    __shared__ float lds[1280];
    int tid = threadIdx.x, bid = blockIdx.x;
    int b = bid & 7, jc = bid >> 3;
    for (int d = tid; d < CDIM; d += 256)
        lds[d] = wsb[OFF_OC + (size_t)b * CDIM + d];
    __syncthreads();
    int j = jc * 32 + (tid & 31), cs = tid >> 5;
    float acc = 0.f;
#pragma unroll 4
    for (int cc = 0; cc < 128; ++cc) {
        int c = cs * 128 + cc;
        acc += lds[c] * Wv[(size_t)c * CDIM + j];
    }
    lds[1024 + cs * 32 + (tid & 31)] = acc;
    __syncthreads();
    if (cs == 0) {
        float a = 0.f;
#pragma unroll
        for (int s8 = 0; s8 < 8; ++s8) a += lds[1024 + s8 * 32 + (tid & 31)];
        out[(size_t)b * CDIM + j] = a + bv[j];
    }
}

extern "C" void kernel_launch(void* const* d_in, const int* in_sizes, int n_in,
                              void* d_out, int out_size, void* d_ws, size_t ws_size,
                              hipStream_t stream) {
    const float* x    = (const float*)d_in[0];   // [8,2048,1024]
    const float* t    = (const float*)d_in[1];   // [1,1,1024]
    const float* W    = (const float*)d_in[2];   // [1024,3072]
    const float* bqkv = (const float*)d_in[3];   // [3072]
    const float* Wv   = (const float*)d_in[4];   // [1024,1024]
    const float* bv   = (const float*)d_in[5];   // [1024]
    float* wsb = (float*)d_ws;
    float* out = (float*)d_out;                  // [8,1024] fp32

    void* args[] = {(void*)&x, (void*)&t, (void*)&W, (void*)&bqkv,
                    (void*)&Wv, (void*)&bv, (void*)&wsb, (void*)&out};

    // Coop path requires grid EXACTLY 1024 (4 blocks/CU). Verify it fits, and
    // verify the launch result; otherwise run the 6-dispatch fallback.
    static int useCoop = 0;   // 0=unknown, 1=yes, -1=no
    if (useCoop == 0) {
        int mb = 0;
        hipError_t qe = hipOccupancyMaxActiveBlocksPerMultiprocessor(&mb, k_fused, 256, 0);
        useCoop = (qe == hipSuccess && mb >= 4) ? 1 : -1;
    }
    if (useCoop == 1) {
        hipError_t e = hipLaunchCooperativeKernel(reinterpret_cast<void*>(k_fused),
                                                  dim3(1024), dim3(256), args, 0, stream);
        if (e == hipSuccess) return;
        useCoop = -1;   // never retry; fall through
    }
    k_p1<<<256,  256, 0, stream>>>(t, W, wsb);
    k_p2<<<1024, 256, 0, stream>>>(W, bqkv, wsb);
    k_p3<<<1024, 256, 0, stream>>>(x, wsb);
    k_p4<<<1024, 256, 0, stream>>>(t, wsb);
    k_p5<<<256,  256, 0, stream>>>(W, bqkv, wsb);
    k_p6<<<256,  256, 0, stream>>>(Wv, bv, wsb, out);
}